// Round 8
// baseline (261.794 us; speedup 1.0000x reference)
//
#include <hip/hip_runtime.h>
#include <hip/hip_bf16.h>
#include <stdint.h>

// Problem constants
#define IN_DIM  512
#define OUT_DIM 512
#define BATCH   16384
#define BM      64               // halved vs R7: grid 512 -> 2 blocks/CU
#define BN      256
#define BK      96               // 8 features * 12 = 3 mfma K-steps of 32
#define KCH     64               // 6144 / 96
#define TSTR    104              // padded A row stride (bf16): 208B
// W3 fragment-major layout: per (g,kc) tile: [rb=0..15][s=0..2][lane=0..63] x 16B
//   unit (rb,s,lane) holds B[row = rb*16 + (lane&15)][k = s*32 + (lane>>4)*8 .. +7]
#define TILE_U  3072             // units per kc-tile (16*3*64)
#define TILE_EL 24576            // bf16 elems per kc-tile

typedef __bf16 bf16;
typedef __bf16 bf16x8 __attribute__((ext_vector_type(8)));
typedef float  f32x4  __attribute__((ext_vector_type(4)));

__device__ __forceinline__ uint bfbits(float v) {
    union { bf16 h; ushort u; } c; c.h = (bf16)v; return (uint)c.u;
}
__device__ __forceinline__ uint pk2(float lo, float hi) {
    return bfbits(lo) | (bfbits(hi) << 16);
}

// ---------------------------------------------------------------------------
// Pack W into MFMA-fragment-major layout W3 (one block per (g,kc) tile).
// Verified R3/R6/R7 (absmax 0.0625). Unmodified.
// ---------------------------------------------------------------------------
__global__ void pack_w(const float* __restrict__ coeff,
                       const float* __restrict__ sbase,
                       const float* __restrict__ sspl,
                       bf16* __restrict__ W3) {
    __shared__ __align__(16) bf16 L[256 * 96];   // 48 KB
    const int t  = threadIdx.x;                  // 0..255
    const int g  = blockIdx.x >> 6;
    const int kc = blockIdx.x & 63;
    const int o  = g * 256 + t;                  // output index
    const float* cp = coeff + ((size_t)o * 512 + kc * 8) * 11;  // 88 consecutive floats
    const float* sp = sspl  + (size_t)o * 512 + kc * 8;
    const float* bp = sbase + (size_t)o * 512 + kc * 8;
    union { bf16 h[96]; uint4 q[12]; } rw;
#pragma unroll
    for (int il = 0; il < 8; ++il) {
        const float s = sp[il];
#pragma unroll
        for (int k = 0; k < 11; ++k) rw.h[il * 12 + k] = (bf16)(cp[il * 11 + k] * s);
        rw.h[il * 12 + 11] = (bf16)bp[il];
    }
    uint4* lrow = (uint4*)(L + t * 96);
#pragma unroll
    for (int j = 0; j < 12; ++j) lrow[j] = rw.q[j];
    __syncthreads();
    uint4* dst = (uint4*)W3 + (size_t)(g * 64 + kc) * TILE_U;
#pragma unroll
    for (int uu = 0; uu < 12; ++uu) {
        const int U   = uu * 256 + t;
        const int rb  = U / 192;
        const int rem = U - rb * 192;
        const int s   = rem >> 6;
        const int li  = rem & 63;
        const int lq  = li >> 4, lr = li & 15;
        dst[U] = *(const uint4*)(L + (rb * 16 + lr) * 96 + s * 32 + lq * 8);
    }
}

// ---------------------------------------------------------------------------
// Fused KAN kernel — R7 structure (verified, 115 us) with BM 128 -> 64:
// grid 512 -> 2 co-resident blocks/CU (R7 had exactly 1 block/CU, so every
// barrier drain was fully exposed; MfmaUtil 39% with no pipe saturated).
// All R7-verified mappings preserved: W3 fragment layout + boff (wn=wave>>1),
// 2m x 4n waves (wm now 32-row halves), single-buffered Bc consume->reload,
// XCD-residence swizzle (g on XCD halves), C/D epilogue mapping.
// Eval: each thread evals ONE feature (row = tid&63, f = tid>>6).
// VGPR ~95 < 128 cap; LDS 26.6 KB/block -> 2 blocks/CU.
// ---------------------------------------------------------------------------

#define LOAD_B(Barr, kcn)                                                     \
  {                                                                           \
    const bf16* _bb = WgB + (size_t)(kcn) * TILE_EL + boff;                   \
    _Pragma("unroll")                                                         \
    for (int f = 0; f < 12; ++f)                                              \
      Barr[f] = *(const bf16x8*)(_bb + (f / 3) * 1536 + (f % 3) * 512);       \
  }

#define EVALP(kcn, Adst)                                                      \
  {                                                                           \
    float _xc = xn;                                                           \
    xn = xrow[(((kcn) + 1) & 63) << 3];                                       \
    evalF(_xc, (Adst));                                                       \
  }

#define MFMA_PH(Ap, Barr)                                                     \
  {                                                                           \
    _Pragma("unroll")                                                         \
    for (int s = 0; s < 3; ++s) {                                             \
      bf16x8 af[2];                                                           \
      _Pragma("unroll")                                                       \
      for (int mt = 0; mt < 2; ++mt)                                          \
        af[mt] = *(const bf16x8*)&(Ap)[(wm * 32 + mt * 16 + lr) * TSTR + s * 32 + lq * 8]; \
      __builtin_amdgcn_s_setprio(1);                                          \
      _Pragma("unroll")                                                       \
      for (int mt = 0; mt < 2; ++mt)                                          \
        _Pragma("unroll")                                                     \
        for (int nt = 0; nt < 4; ++nt)                                        \
          acc[mt][nt] = __builtin_amdgcn_mfma_f32_16x16x32_bf16(              \
              af[mt], Barr[nt * 3 + s], acc[mt][nt], 0, 0, 0);                \
      __builtin_amdgcn_s_setprio(0);                                          \
    }                                                                         \
  }

__global__ void __launch_bounds__(512, 2) kan_gemm(
    const float* __restrict__ xg,
    const float* __restrict__ gridp,
    const float* __restrict__ bias,
    const bf16*  __restrict__ W3,
    float* __restrict__ out)
{
    __shared__ bf16 Abuf[2 * BM * TSTR];   // 26624 B (A double buffer only)

    const int tid  = threadIdx.x;
    const int lane = tid & 63;
    const int wave = tid >> 6;
    // XCD-residence swizzle (grid = 512 linear blocks, bid%8 -> XCD):
    //   bid = 8u + 4g + c  ->  XCDs 0-3 get g=0, XCDs 4-7 get g=1;
    //   mt_ = 4u + c bijective over 256 m-tiles per g.
    const int bid = blockIdx.x;
    const int g   = (bid >> 2) & 1;
    const int mt_ = (bid >> 3) * 4 + (bid & 3);
    const int n0 = g * BN;
    const int m0 = mt_ * BM;

    const float g0    = gridp[0];
    const float inv_h = 1.0f / (gridp[1] - gridp[0]);

    const bf16* WgB = W3 + (size_t)g * KCH * TILE_EL;

    // eval assignment: 1 feature per thread (64 rows x 8 features per kc)
    const int row_e = tid & 63;
    const int fe    = tid >> 6;            // 0..7 -> feature kc*8 + fe
    const float* xrow = xg + (size_t)(m0 + row_e) * IN_DIM + fe;
    // x(kc) for this thread = xrow[kc*8]

    // MFMA wave layout (2m x 4n of 32x64 tiles)
    const int wm = wave & 1, wn = wave >> 1;
    const int lr = lane & 15, lq = lane >> 4;
    const bool mfirst = (wave >= 4);       // one eval-first + one mfma-first per SIMD
    const int boff = wn * 6144 + lane * 8; // fragment-major per-lane B offset (elems)

    bf16* const Ab0 = Abuf;
    bf16* const Ab1 = Abuf + BM * TSTR;

    f32x4 acc[2][4];
#pragma unroll
    for (int mt = 0; mt < 2; ++mt)
#pragma unroll
        for (int nt = 0; nt < 4; ++nt) { f32x4 z = {0.f, 0.f, 0.f, 0.f}; acc[mt][nt] = z; }

    bf16x8 Bc[12];                         // single-buffered B fragments
    float xn;

    // one local B-spline eval -> 6 packed dwords
    auto evalOne = [&](float xv, uint* De) {
        float f  = __builtin_fmaf(xv, inv_h, -g0 * inv_h);
        f = fminf(fmaxf(f, 7.0f), 14.9999f);
        float fj = floorf(f);
        int   j0 = (int)fj;
        float t  = f - fj;
        float t1 = t + 1.0f, t2 = t + 2.0f, t3 = t + 3.0f;
        float s1 = 1.0f - t, s2 = 2.0f - t, s3 = 3.0f - t, s4 = 4.0f - t;
        float a0 = 0.5f * t, a1 = 0.5f * s1;
        const float i3 = (1.0f / 3.0f);
        float b0 = t  * a0 * i3;
        float b1 = (t1 * a1 + s2 * a0) * i3;
        float b2 = s1 * a1 * i3;
        float c0 = t  * b0 * 0.25f;
        float c1 = (t1 * b1 + s3 * b0) * 0.25f;
        float c2 = (t2 * b2 + s2 * b1) * 0.25f;
        float c3 = s1 * b2 * 0.25f;
        float w0 = t  * c0 * 0.2f;
        float w1 = (t1 * c1 + s4 * c0) * 0.2f;
        float w2 = (t2 * c2 + s3 * c1) * 0.2f;
        float w3 = (t3 * c3 + s2 * c2) * 0.2f;
        float w4 = s1 * c3 * 0.2f;
        const int q0 = j0 - 4;             // [3,10]
        const int rr = q0 & 1;
        const int d  = q0 >> 1;            // [1,5]
        uint P0 = pk2(w4, w3), P1 = pk2(w2, w1), P2 = bfbits(w0);
        uint A0 = rr ? (P0 << 16)                : P0;
        uint A1 = rr ? ((P0 >> 16) | (P1 << 16)) : P1;
        uint A2 = rr ? ((P1 >> 16) | (P2 << 16)) : P2;
        De[0] = 0u;
        De[1] = (d == 1) ? A0 : 0u;
        De[2] = (d == 2) ? A0 : ((d == 1) ? A1 : 0u);
        De[3] = (d == 3) ? A0 : ((d == 2) ? A1 : ((d == 1) ? A2 : 0u));
        De[4] = (d == 4) ? A0 : ((d == 3) ? A1 : ((d == 2) ? A2 : 0u));
        uint D5 = (d == 5) ? A0 : ((d == 4) ? A1 : ((d == 3) ? A2 : 0u));
        De[5] = (D5 & 0xFFFFu) | (bfbits(xv + __sinf(xv)) << 16);
    };
    auto evalF = [&](float xc, bf16* Adst) {
        uint D[6];
        evalOne(xc, D);
        uint2* awr = (uint2*)(Adst + row_e * TSTR + fe * 12);  // 24B, 8B-aligned
        awr[0] = make_uint2(D[0], D[1]);
        awr[1] = make_uint2(D[2], D[3]);
        awr[2] = make_uint2(D[4], D[5]);
    };

    // Prologue: B(0) -> Bc, eval(0) -> Ab0, xn = x(1)
    LOAD_B(Bc, 0);
    {
        float xc0 = xrow[0];
        xn = xrow[8];
        evalF(xc0, Ab0);
    }
    __syncthreads();

    for (int kc = 0; kc < KCH; ++kc) {
        const int p = kc & 1;
        const bf16* Ap = p ? Ab1 : Ab0;
        bf16*       An = p ? Ab0 : Ab1;
        if (mfirst) {
            MFMA_PH(Ap, Bc);
            if (kc < KCH - 1) {
                LOAD_B(Bc, kc + 1);        // in flight under the eval below
                EVALP(kc + 1, An);
            }
        } else {
            if (kc < KCH - 1) EVALP(kc + 1, An);
            MFMA_PH(Ap, Bc);
            if (kc < KCH - 1) LOAD_B(Bc, kc + 1);
        }
        __syncthreads();   // buffer p free; p^1 eval-writes visible
    }

    // Epilogue: C/D layout col = lane&15, row = (lane>>4)*4 + reg
#pragma unroll
    for (int nt = 0; nt < 4; ++nt) {
        const int gcol = n0 + wn * 64 + nt * 16 + lr;
        const float bv = bias[gcol];
#pragma unroll
        for (int mt = 0; mt < 2; ++mt) {
#pragma unroll
            for (int i = 0; i < 4; ++i) {
                const int grow = m0 + wm * 32 + mt * 16 + lq * 4 + i;
                out[(size_t)grow * OUT_DIM + gcol] = acc[mt][nt][i] + bv;
            }
        }
    }
}

// ---------------------------------------------------------------------------
extern "C" void kernel_launch(void* const* d_in, const int* in_sizes, int n_in,
                              void* d_out, int out_size, void* d_ws, size_t ws_size,
                              hipStream_t stream) {
    const float* x     = (const float*)d_in[0];
    const float* gridv = (const float*)d_in[1];
    const float* coeff = (const float*)d_in[2];
    const float* sbase = (const float*)d_in[3];
    const float* sspl  = (const float*)d_in[4];
    const float* bias  = (const float*)d_in[5];
    float* out = (float*)d_out;
    bf16*  W3  = (bf16*)d_ws;   // 2 * 64 * 24576 * 2B = 6.0 MB workspace

    pack_w<<<dim3(128), 256, 0, stream>>>(coeff, sbase, sspl, W3);
    kan_gemm<<<dim3(512), 512, 0, stream>>>(x, gridv, bias, W3, out);
}

// Round 9
// 193.500 us; speedup vs baseline: 1.3529x; 1.3529x over previous
//
#include <hip/hip_runtime.h>
#include <hip/hip_bf16.h>
#include <stdint.h>

// Problem constants
#define IN_DIM  512
#define OUT_DIM 512
#define BATCH   16384
#define BM      128
#define BN      256
#define BK      96               // 8 features * 12 = 3 mfma K-steps of 32
#define KCH     64               // 6144 / 96
#define TSTR    104              // padded A row stride (bf16): 208B
// W3 fragment-major layout: per (g,kc) tile: [rb=0..15][s=0..2][lane=0..63] x 16B
//   unit (rb,s,lane) holds B[row = rb*16 + (lane&15)][k = s*32 + (lane>>4)*8 .. +7]
#define TILE_U  3072             // units per kc-tile (16*3*64)
#define TILE_EL 24576            // bf16 elems per kc-tile

typedef __bf16 bf16;
typedef __bf16 bf16x8 __attribute__((ext_vector_type(8)));
typedef float  f32x4  __attribute__((ext_vector_type(4)));

__device__ __forceinline__ uint bfbits(float v) {
    union { bf16 h; ushort u; } c; c.h = (bf16)v; return (uint)c.u;
}
__device__ __forceinline__ uint pk2(float lo, float hi) {
    return bfbits(lo) | (bfbits(hi) << 16);
}

// ---------------------------------------------------------------------------
// Pack W into MFMA-fragment-major layout W3 (one block per (g,kc) tile).
// Verified R3/R6/R7 (absmax 0.0625). Unmodified.
// ---------------------------------------------------------------------------
__global__ void pack_w(const float* __restrict__ coeff,
                       const float* __restrict__ sbase,
                       const float* __restrict__ sspl,
                       bf16* __restrict__ W3) {
    __shared__ __align__(16) bf16 L[256 * 96];   // 48 KB
    const int t  = threadIdx.x;                  // 0..255
    const int g  = blockIdx.x >> 6;
    const int kc = blockIdx.x & 63;
    const int o  = g * 256 + t;                  // output index
    const float* cp = coeff + ((size_t)o * 512 + kc * 8) * 11;  // 88 consecutive floats
    const float* sp = sspl  + (size_t)o * 512 + kc * 8;
    const float* bp = sbase + (size_t)o * 512 + kc * 8;
    union { bf16 h[96]; uint4 q[12]; } rw;
#pragma unroll
    for (int il = 0; il < 8; ++il) {
        const float s = sp[il];
#pragma unroll
        for (int k = 0; k < 11; ++k) rw.h[il * 12 + k] = (bf16)(cp[il * 11 + k] * s);
        rw.h[il * 12 + 11] = (bf16)bp[il];
    }
    uint4* lrow = (uint4*)(L + t * 96);
#pragma unroll
    for (int j = 0; j < 12; ++j) lrow[j] = rw.q[j];
    __syncthreads();
    uint4* dst = (uint4*)W3 + (size_t)(g * 64 + kc) * TILE_U;
#pragma unroll
    for (int uu = 0; uu < 12; ++uu) {
        const int U   = uu * 256 + t;
        const int rb  = U / 192;
        const int rem = U - rb * 192;
        const int s   = rem >> 6;
        const int li  = rem & 63;
        const int lq  = li >> 4, lr = li & 15;
        dst[U] = *(const uint4*)(L + (rb * 16 + lr) * 96 + s * 32 + lq * 8);
    }
}

// ---------------------------------------------------------------------------
// Fused KAN kernel — R7's verified structure (115 us, absmax 0.0625) with the
// barrier granularity COARSENED to 2 k-chunks per phase:
//  - R7 paid ~2450 cyc of per-barrier overhead (eval dep chain, vmcnt drain
//    of B loads, ds_read latency, skew) PER kc. 32 phases instead of 64
//    halves that bill; the mid-phase B reload hides under an eval (~600 cyc)
//    instead of a barrier drain.
//  - LDS: 2 phase-buffers x 2 kc x 128 x 104 = 106.5 KB (1 block/CU — which
//    is all the dispatcher ever gives us; R8 proved 2 blocks never co-reside).
// All mappings identical to R7: W3 fragment layout + boff (wn=wave>>1),
// 2m x 4n waves, single-buffered Bc consume->reload, XCD-residence swizzle,
// C/D epilogue. Eval: 2 features/thread/kc (row=tid&127, fpair=tid>>7).
// ---------------------------------------------------------------------------

#define LOAD_B(Barr, kcn)                                                     \
  {                                                                           \
    const bf16* _bb = WgB + (size_t)(kcn) * TILE_EL + boff;                   \
    _Pragma("unroll")                                                         \
    for (int f = 0; f < 12; ++f)                                              \
      Barr[f] = *(const bf16x8*)(_bb + (f / 3) * 1536 + (f % 3) * 512);       \
  }

#define MFMA_PH(Ap, Barr)                                                     \
  {                                                                           \
    _Pragma("unroll")                                                         \
    for (int s = 0; s < 3; ++s) {                                             \
      bf16x8 af[4];                                                           \
      _Pragma("unroll")                                                       \
      for (int mt = 0; mt < 4; ++mt)                                          \
        af[mt] = *(const bf16x8*)&(Ap)[(wm * 64 + mt * 16 + lr) * TSTR + s * 32 + lq * 8]; \
      __builtin_amdgcn_s_setprio(1);                                          \
      _Pragma("unroll")                                                       \
      for (int mt = 0; mt < 4; ++mt)                                          \
        _Pragma("unroll")                                                     \
        for (int nt = 0; nt < 4; ++nt)                                        \
          acc[mt][nt] = __builtin_amdgcn_mfma_f32_16x16x32_bf16(              \
              af[mt], Barr[nt * 3 + s], acc[mt][nt], 0, 0, 0);                \
      __builtin_amdgcn_s_setprio(0);                                          \
    }                                                                         \
  }

__global__ void __launch_bounds__(512, 2) kan_gemm(
    const float* __restrict__ xg,
    const float* __restrict__ gridp,
    const float* __restrict__ bias,
    const bf16*  __restrict__ W3,
    float* __restrict__ out)
{
    // [phase-buf][kc-within-phase][row][col]
    __shared__ bf16 Abuf[2 * 2 * BM * TSTR];   // 106496 B

    const int tid  = threadIdx.x;
    const int lane = tid & 63;
    const int wave = tid >> 6;
    // XCD-residence swizzle (grid = 256 linear blocks, bid%8 -> XCD):
    //   XCDs 0-3 get g=0, XCDs 4-7 get g=1; 128 m-tiles per g.
    const int bid = blockIdx.x;
    const int g   = (bid >> 2) & 1;
    const int mt_ = (bid >> 3) * 4 + (bid & 3);
    const int n0 = g * BN;
    const int m0 = mt_ * BM;

    const float g0    = gridp[0];
    const float inv_h = 1.0f / (gridp[1] - gridp[0]);

    const bf16* WgB = W3 + (size_t)g * KCH * TILE_EL;

    // eval assignment: 2 features per thread (128 rows x 8 features per kc)
    const int row_e = tid & 127;
    const int fpair = tid >> 7;            // 0..3 -> features fpair*2, fpair*2+1
    const float* xrow = xg + (size_t)(m0 + row_e) * IN_DIM + fpair * 2;

    // MFMA wave layout (2m x 4n of 64x64 tiles)
    const int wm = wave & 1, wn = wave >> 1;
    const int lr = lane & 15, lq = lane >> 4;
    const bool mfirst = (wave >= 4);       // one eval-first + one mfma-first per SIMD
    const int boff = wn * 6144 + lane * 8; // fragment-major per-lane B offset (elems)

    f32x4 acc[4][4];
#pragma unroll
    for (int mt = 0; mt < 4; ++mt)
#pragma unroll
        for (int nt = 0; nt < 4; ++nt) { f32x4 z = {0.f, 0.f, 0.f, 0.f}; acc[mt][nt] = z; }

    bf16x8 Bc[12];                         // single-buffered B fragments
    float2 xnA, xnB;                       // prefetched x for next phase's two evals

    // one local B-spline eval -> 6 packed dwords
    auto evalOne = [&](float xv, uint* De) {
        float f  = __builtin_fmaf(xv, inv_h, -g0 * inv_h);
        f = fminf(fmaxf(f, 7.0f), 14.9999f);
        float fj = floorf(f);
        int   j0 = (int)fj;
        float t  = f - fj;
        float t1 = t + 1.0f, t2 = t + 2.0f, t3 = t + 3.0f;
        float s1 = 1.0f - t, s2 = 2.0f - t, s3 = 3.0f - t, s4 = 4.0f - t;
        float a0 = 0.5f * t, a1 = 0.5f * s1;
        const float i3 = (1.0f / 3.0f);
        float b0 = t  * a0 * i3;
        float b1 = (t1 * a1 + s2 * a0) * i3;
        float b2 = s1 * a1 * i3;
        float c0 = t  * b0 * 0.25f;
        float c1 = (t1 * b1 + s3 * b0) * 0.25f;
        float c2 = (t2 * b2 + s2 * b1) * 0.25f;
        float c3 = s1 * b2 * 0.25f;
        float w0 = t  * c0 * 0.2f;
        float w1 = (t1 * c1 + s4 * c0) * 0.2f;
        float w2 = (t2 * c2 + s3 * c1) * 0.2f;
        float w3 = (t3 * c3 + s2 * c2) * 0.2f;
        float w4 = s1 * c3 * 0.2f;
        const int q0 = j0 - 4;             // [3,10]
        const int rr = q0 & 1;
        const int d  = q0 >> 1;            // [1,5]
        uint P0 = pk2(w4, w3), P1 = pk2(w2, w1), P2 = bfbits(w0);
        uint A0 = rr ? (P0 << 16)                : P0;
        uint A1 = rr ? ((P0 >> 16) | (P1 << 16)) : P1;
        uint A2 = rr ? ((P1 >> 16) | (P2 << 16)) : P2;
        De[0] = 0u;
        De[1] = (d == 1) ? A0 : 0u;
        De[2] = (d == 2) ? A0 : ((d == 1) ? A1 : 0u);
        De[3] = (d == 3) ? A0 : ((d == 2) ? A1 : ((d == 1) ? A2 : 0u));
        De[4] = (d == 4) ? A0 : ((d == 3) ? A1 : ((d == 2) ? A2 : 0u));
        uint D5 = (d == 5) ? A0 : ((d == 4) ? A1 : ((d == 3) ? A2 : 0u));
        De[5] = (D5 & 0xFFFFu) | (bfbits(xv + __sinf(xv)) << 16);
    };
    auto evalPair = [&](float2 xc, bf16* Adst) {
        uint D[12];
        evalOne(xc.x, D);
        evalOne(xc.y, D + 6);
        uint4* awr = (uint4*)(Adst + row_e * TSTR + fpair * 24);  // 48B, 16B-aligned
        awr[0] = make_uint4(D[0], D[1], D[2],  D[3]);
        awr[1] = make_uint4(D[4], D[5], D[6],  D[7]);
        awr[2] = make_uint4(D[8], D[9], D[10], D[11]);
    };

    // Prologue: B(0) -> Bc; eval kc0,kc1 -> phase-buf 0; prefetch x(2),x(3)
    LOAD_B(Bc, 0);
    {
        float2 xc0 = *(const float2*)(xrow);
        float2 xc1 = *(const float2*)(xrow + 8);
        xnA = *(const float2*)(xrow + 16);
        xnB = *(const float2*)(xrow + 24);
        evalPair(xc0, Abuf);
        evalPair(xc1, Abuf + BM * TSTR);
    }
    __syncthreads();

    for (int ph = 0; ph < 32; ++ph) {
        const int pb = ph & 1;
        const bf16* Ap0 = Abuf + (pb * 2 + 0) * BM * TSTR;   // kc = 2ph
        const bf16* Ap1 = Abuf + (pb * 2 + 1) * BM * TSTR;   // kc = 2ph+1
        bf16* An0 = Abuf + ((pb ^ 1) * 2 + 0) * BM * TSTR;   // kc = 2ph+2
        bf16* An1 = Abuf + ((pb ^ 1) * 2 + 1) * BM * TSTR;   // kc = 2ph+3
        const int kc0 = 2 * ph;
        const bool more = (ph < 31);

        if (mfirst) {
            MFMA_PH(Ap0, Bc);              // consumes B(kc0)
            LOAD_B(Bc, kc0 + 1);           // in flight under eval below
            if (more) {
                float2 xc = xnA;
                xnA = *(const float2*)(xrow + (((kc0 + 4) & 63) << 3));
                evalPair(xc, An0);
            }
            MFMA_PH(Ap1, Bc);              // consumes B(kc0+1)
            if (more) {
                LOAD_B(Bc, kc0 + 2);       // drained by the barrier below
                float2 xc = xnB;
                xnB = *(const float2*)(xrow + (((kc0 + 5) & 63) << 3));
                evalPair(xc, An1);
            }
        } else {
            if (more) {
                float2 xc = xnA;
                xnA = *(const float2*)(xrow + (((kc0 + 4) & 63) << 3));
                evalPair(xc, An0);
            }
            MFMA_PH(Ap0, Bc);
            LOAD_B(Bc, kc0 + 1);
            if (more) {
                float2 xc = xnB;
                xnB = *(const float2*)(xrow + (((kc0 + 5) & 63) << 3));
                evalPair(xc, An1);
            }
            MFMA_PH(Ap1, Bc);
            if (more) LOAD_B(Bc, kc0 + 2);
        }
        __syncthreads();   // phase buffer swap; next-phase A + B(kc0+2) ready
    }

    // Epilogue: C/D layout col = lane&15, row = (lane>>4)*4 + reg
#pragma unroll
    for (int nt = 0; nt < 4; ++nt) {
        const int gcol = n0 + wn * 64 + nt * 16 + lr;
        const float bv = bias[gcol];
#pragma unroll
        for (int mt = 0; mt < 4; ++mt) {
#pragma unroll
            for (int i = 0; i < 4; ++i) {
                const int grow = m0 + wm * 64 + mt * 16 + lq * 4 + i;
                out[(size_t)grow * OUT_DIM + gcol] = acc[mt][nt][i] + bv;
            }
        }
    }
}

// ---------------------------------------------------------------------------
extern "C" void kernel_launch(void* const* d_in, const int* in_sizes, int n_in,
                              void* d_out, int out_size, void* d_ws, size_t ws_size,
                              hipStream_t stream) {
    const float* x     = (const float*)d_in[0];
    const float* gridv = (const float*)d_in[1];
    const float* coeff = (const float*)d_in[2];
    const float* sbase = (const float*)d_in[3];
    const float* sspl  = (const float*)d_in[4];
    const float* bias  = (const float*)d_in[5];
    float* out = (float*)d_out;
    bf16*  W3  = (bf16*)d_ws;   // 2 * 64 * 24576 * 2B = 6.0 MB workspace

    pack_w<<<dim3(128), 256, 0, stream>>>(coeff, sbase, sspl, W3);
    kan_gemm<<<dim3(256), 512, 0, stream>>>(x, gridv, bias, W3, out);
}